// Round 7
// baseline (545.226 us; speedup 1.0000x reference)
//
#include <hip/hip_runtime.h>

#define NN 4096
#define EPS 1e-5f

// ---------------- workspace layout (float offsets) ----------------
#define Q_OFF   0u              // [B][N][8]      131072
#define K_OFF   131072u         // [B][8][N]      131072
#define V_OFF   262144u         // [B][64][N]    1048576
#define O_OFF   1310720u        // PAM out [B][64][N]
#define Y_OFF   2359296u        // y [B][64][N]
#define OC_OFF  3407872u        // CAM raw out
#define AT_OFF  4456448u        // attn_c [B][64][64] 16384
#define S2_OFF  4472832u        // CAM sums: sum[64], sumsq[64]
#define PS_OFF  4472960u        // PAM sums: sum[64], sumsq[64]
#define GP_OFF  4473088u        // gram partials [B*64][64][64] (1048576)

// ---------------- projections: q,k,v (x staged via LDS) ----------------
// (verbatim round 6 — passed)
__global__ __launch_bounds__(256) void proj_kernel(
    const float* __restrict__ x, const float* __restrict__ Wq, const float* __restrict__ bq,
    const float* __restrict__ Wk, const float* __restrict__ bk,
    const float* __restrict__ Wv, const float* __restrict__ bv,
    float* __restrict__ q, float* __restrict__ k, float* __restrict__ v) {
  __shared__ float sWq[8*64], sWk[8*64], sWv[64*64], sbq[8], sbk[8], sbv[64];
  __shared__ float xt[64*68];
  int t = threadIdx.x;
  int b = blockIdx.x >> 6;
  int sp = blockIdx.x & 63;
  int n0 = sp << 6;
  for (int i = t; i < 512; i += 256) { sWq[i] = Wq[i]; sWk[i] = Wk[i]; }
  for (int i = t; i < 4096; i += 256) sWv[i] = Wv[i];
  if (t < 64) sbv[t] = bv[t];
  if (t < 8) { sbq[t] = bq[t]; sbk[t] = bk[t]; }
  for (int i = t; i < 1024; i += 256) {
    int c = i >> 4, nf = (i & 15) << 2;
    *(float4*)&xt[c*68 + nf] =
        *(const float4*)&x[(size_t)(((b<<6)|c)<<12) + n0 + nf];
  }
  __syncthreads();
  int nl = t & 63;
  int n = n0 | nl;
  int cg_ = t >> 6;
  float xv[64];
  #pragma unroll
  for (int c = 0; c < 64; ++c) xv[c] = xt[c*68 + nl];
  for (int c = cg_*16; c < cg_*16+16; ++c) {
    float acc = sbv[c];
    #pragma unroll
    for (int c2 = 0; c2 < 64; ++c2) acc += sWv[c*64 + c2] * xv[c2];
    v[(((b<<6)|c)<<12) | n] = acc;
  }
  if (cg_ == 0) {
    #pragma unroll
    for (int d = 0; d < 8; ++d) {
      float acc = sbq[d];
      #pragma unroll
      for (int c = 0; c < 64; ++c) acc += sWq[d*64+c] * xv[c];
      q[(((b<<12)|n)<<3) | d] = acc;
    }
  } else if (cg_ == 1) {
    #pragma unroll
    for (int d = 0; d < 8; ++d) {
      float acc = sbk[d];
      #pragma unroll
      for (int c = 0; c < 64; ++c) acc += sWk[d*64+c] * xv[c];
      k[(((b<<3)|d)<<12) | n] = acc;
    }
  }
}

// ---------------- flash attention (PAM): full sweep, reg-staged dbuf ----
// grid 256 = (b, mt) via XCD swizzle; 256 threads; r2's 4x4-tile per-thread
// code; K/V double-buffered in LDS with REGISTER staging: iter i issues the
// 18 global loads for chunk i+1 up front, computes scores+PV on buf[cur],
// then ds_writes the staged regs to buf[nxt].  2 barriers/iter.  All blocks
// sweep n in lockstep from 0 -> tiny shared L2 window; XCD swizzle gives
// each XCD one batch only (cuts L2 fill ~3x vs r6).  No partials, no merge.
__global__ __launch_bounds__(256, 1) void attn_kernel(
    const float* __restrict__ q, const float* __restrict__ k,
    const float* __restrict__ v, float* __restrict__ o,
    float* __restrict__ psums) {
  __shared__ float kst[2][64*12];   // [ni][d], pad 12
  __shared__ float vst[2][64*68];   // [ni][c], pad 68
  __shared__ float pst[64*68];      // [ni][m], pad 68 (+ scratch)

  // XCD swizzle: xcd = bi&7 serves one batch (b = xcd>>1)
  const int bi = blockIdx.x;
  const int xcd = bi & 7, j = bi >> 3;
  const int b  = xcd >> 1;
  const int mt = ((xcd & 1) << 5) | j;
  const int m0 = mt << 6;
  const int t  = threadIdx.x;

  const int rq = t & 15;        // score: rows 4rq..4rq+3 ; PV: cols 4rq..
  const int sg = t >> 4;        // score: ni 4sg..4sg+3   ; PV: rows 4sg..

  float4 qa[4][2];
  #pragma unroll
  for (int r = 0; r < 4; ++r) {
    const float4* qp = (const float4*)&q[(size_t)(((b<<12) | (m0 + (rq<<2) + r)) << 3)];
    qa[r][0] = qp[0]; qa[r][1] = qp[1];
  }

  float lsum[4] = {0.f, 0.f, 0.f, 0.f};
  float av[4][4] = {{0.f}};

  // staging index helpers (fixed per thread)
  const int kd0 = t >> 6, kn0 = t & 63;          // K elem 1: (d=kd0, ni=kn0)
  const int kd1 = kd0 + 4;                       // K elem 2
  const size_t kgb = (size_t)(b << 3) << 12;
  const size_t vgb = (size_t)(b << 6) << 12;

  // prologue: stage chunk 0 directly
  kst[0][kn0*12 + kd0] = k[kgb + ((size_t)kd0<<12) + kn0];
  kst[0][kn0*12 + kd1] = k[kgb + ((size_t)kd1<<12) + kn0];
  #pragma unroll
  for (int jj = 0; jj < 16; ++jj) {
    int i = (jj<<8) + t;
    int ni = i & 63, c = i >> 6;
    vst[0][ni*68 + c] = v[vgb + ((size_t)c<<12) + ni];
  }
  __syncthreads();

  int cur = 0;
  for (int it = 0; it < 64; ++it) {
    const int nxt = cur ^ 1;
    const int n1 = (it + 1) << 6;
    const bool more = (it < 63);
    // issue next-chunk global loads into registers (latency hides under compute)
    float kreg0, kreg1, vreg[16];
    if (more) {
      kreg0 = k[kgb + ((size_t)kd0<<12) + n1 + kn0];
      kreg1 = k[kgb + ((size_t)kd1<<12) + n1 + kn0];
      #pragma unroll
      for (int jj = 0; jj < 16; ++jj) {
        int i = (jj<<8) + t;
        int ni = i & 63, c = i >> 6;
        vreg[jj] = v[vgb + ((size_t)c<<12) + n1 + ni];
      }
    }
    // scores: thread (rq, sg) -> rows 4rq.., ni 4sg..4sg+3 (from kst[cur])
    #pragma unroll
    for (int jj = 0; jj < 4; ++jj) {
      const int ni = (sg << 2) | jj;
      const float4 ka = *(const float4*)&kst[cur][ni*12];
      const float4 kb = *(const float4*)&kst[cur][ni*12 + 4];
      float pj[4];
      #pragma unroll
      for (int r = 0; r < 4; ++r) {
        float s = qa[r][0].x*ka.x + qa[r][0].y*ka.y + qa[r][0].z*ka.z + qa[r][0].w*ka.w
                + qa[r][1].x*kb.x + qa[r][1].y*kb.y + qa[r][1].z*kb.z + qa[r][1].w*kb.w;
        float e = __expf(s);     // no-max softmax (validated r1-r6)
        pj[r] = e;
        lsum[r] += e;
      }
      *(float4*)&pst[ni*68 + (rq<<2)] = make_float4(pj[0], pj[1], pj[2], pj[3]);
    }
    __syncthreads();             // pst ready (kst[cur] reads done)
    // PV: thread (sg=m-group, rq=c-group), 4x4 tile (from vst[cur])
    #pragma unroll 4
    for (int ni = 0; ni < 64; ++ni) {
      const float4 p4 = *(const float4*)&pst[ni*68 + (sg<<2)];
      const float4 v4 = *(const float4*)&vst[cur][ni*68 + (rq<<2)];
      av[0][0] += p4.x*v4.x; av[0][1] += p4.x*v4.y; av[0][2] += p4.x*v4.z; av[0][3] += p4.x*v4.w;
      av[1][0] += p4.y*v4.x; av[1][1] += p4.y*v4.y; av[1][2] += p4.y*v4.z; av[1][3] += p4.y*v4.w;
      av[2][0] += p4.z*v4.x; av[2][1] += p4.z*v4.y; av[2][2] += p4.z*v4.z; av[2][3] += p4.z*v4.w;
      av[3][0] += p4.w*v4.x; av[3][1] += p4.w*v4.y; av[3][2] += p4.w*v4.z; av[3][3] += p4.w*v4.w;
    }
    // commit staged regs to buf[nxt] (waits vmcnt here, after compute)
    if (more) {
      kst[nxt][kn0*12 + kd0] = kreg0;
      kst[nxt][kn0*12 + kd1] = kreg1;
      #pragma unroll
      for (int jj = 0; jj < 16; ++jj) {
        int i = (jj<<8) + t;
        int ni = i & 63, c = i >> 6;
        vst[nxt][ni*68 + c] = vreg[jj];
      }
    }
    __syncthreads();             // buf[nxt] ready; vst[cur]/pst reads done
    cur = nxt;
  }

  // ---- epilogue: reduce denominators, normalize, transpose, store ----
  // lsum partials into pst scratch: pst[sg][row]
  *(float4*)&pst[sg*68 + (rq<<2)] = make_float4(lsum[0], lsum[1], lsum[2], lsum[3]);
  __syncthreads();
  if (t < 64) {
    float l = 0.f;
    #pragma unroll
    for (int s = 0; s < 16; ++s) l += pst[s*68 + t];
    kst[0][t] = 1.f / l;         // linv
  }
  __syncthreads();
  {  // normalize + transpose into sm = vst[0] as [c][m] pad 65
    float* sm = vst[0];
    #pragma unroll
    for (int r = 0; r < 4; ++r) {
      const int m = (sg<<2) + r;
      const float inv = kst[0][m];
      #pragma unroll
      for (int cc = 0; cc < 4; ++cc)
        sm[((rq<<2)+cc)*65 + m] = av[r][cc] * inv;
    }
  }
  __syncthreads();
  {  // coalesced o store + fused BN1 stats (wave-uniform c)
    const float* sm = vst[0];
    for (int i = 0; i < 16; ++i) {
      int idx = (i<<8) + t;
      int m = idx & 63, c = idx >> 6;
      float ov = sm[c*65 + m];
      o[(size_t)(((b<<6)|c)<<12) + m0 + m] = ov;
      float s1 = ov, s2 = ov*ov;
      #pragma unroll
      for (int off = 32; off; off >>= 1) {
        s1 += __shfl_xor(s1, off, 64);
        s2 += __shfl_xor(s2, off, 64);
      }
      if ((t & 63) == 0) { atomicAdd(&psums[c], s1); atomicAdd(&psums[64+c], s2); }
    }
  }
}

// ---------------- yg: BN1 coefs + y = o*A1+B1+x + gram partials ----------------
// (verbatim round 4/6 — passed)
__global__ __launch_bounds__(256) void yg_kernel(
    const float* __restrict__ o, const float* __restrict__ x,
    const float* __restrict__ psums,
    const float* __restrict__ gp, const float* __restrict__ w1, const float* __restrict__ bb1,
    float* __restrict__ y, float* __restrict__ gpart) {
  __shared__ float yt[64*68];    // [c][m]
  __shared__ float cf[128];
  const int bi = blockIdx.x;
  const int b = bi >> 6, sp = bi & 63;
  const int t = threadIdx.x;
  const int n0 = sp << 6;
  if (t < 64) {
    float m1 = psums[t] * (1.f/16384.f), m2 = psums[64+t] * (1.f/16384.f);
    float var = m2 - m1*m1;
    float gg = *gp;
    float r = rsqrtf(gg*gg*var + EPS);
    float a = gg * r * w1[t];
    cf[t] = a; cf[64+t] = bb1[t] - m1*a;
  }
  __syncthreads();
  #pragma unroll
  for (int i = 0; i < 16; ++i) {
    int idx = (i<<8) + t;
    int c = idx >> 6, m = idx & 63;    // c wave-uniform, m coalesced
    size_t gi = ((size_t)(((b<<6)|c)<<12)) + n0 + m;
    float yv = o[gi]*cf[c] + cf[64+c] + x[gi];
    yt[c*68 + m] = yv;
    y[gi] = yv;
  }
  __syncthreads();
  {
    int tc = t >> 4, td = t & 15;
    float acc[4][4] = {{0.f}};
    #pragma unroll
    for (int mj = 0; mj < 16; ++mj) {
      float4 ya[4], yb[4];
      #pragma unroll
      for (int r = 0; r < 4; ++r)  ya[r] = *(const float4*)&yt[((tc<<2)+r)*68 + (mj<<2)];
      #pragma unroll
      for (int ss = 0; ss < 4; ++ss) yb[ss] = *(const float4*)&yt[((td<<2)+ss)*68 + (mj<<2)];
      #pragma unroll
      for (int r = 0; r < 4; ++r)
        #pragma unroll
        for (int ss = 0; ss < 4; ++ss)
          acc[r][ss] += ya[r].x*yb[ss].x + ya[r].y*yb[ss].y + ya[r].z*yb[ss].z + ya[r].w*yb[ss].w;
    }
    float* gb = gpart + ((size_t)bi << 12);
    #pragma unroll
    for (int r = 0; r < 4; ++r)
      *(float4*)&gb[(((tc<<2)+r)<<6) | (td<<2)] =
          make_float4(acc[r][0], acc[r][1], acc[r][2], acc[r][3]);
  }
}

// ---------------- csm: reduce gram partials + row softmax -> attnc ----------------
// (verbatim round 4/6 — passed)
__global__ __launch_bounds__(256) void csm_kernel(
    const float* __restrict__ gpart, float* __restrict__ attnc) {
  __shared__ float red[256];
  const int bi = blockIdx.x;
  const int b = bi >> 6, row = bi & 63;
  const int t = threadIdx.x;
  const int d = t & 63, spg = t >> 6;
  float e = 0.f;
  #pragma unroll
  for (int jj = 0; jj < 16; ++jj) {
    int spp = (spg<<4) + jj;
    e += gpart[((size_t)((b<<6)|spp) << 12) + (row<<6) + d];
  }
  red[t] = e;
  __syncthreads();
  if (t < 64) {
    float ee = red[t]+red[64+t]+red[128+t]+red[192+t];
    float mn = ee;
    #pragma unroll
    for (int off = 32; off; off >>= 1) mn = fminf(mn, __shfl_xor(mn, off, 64));
    float p = __expf(mn - ee);           // softmax(max-e) == exp(min-e)/sum
    float s = p;
    #pragma unroll
    for (int off = 32; off; off >>= 1) s += __shfl_xor(s, off, 64);
    attnc[(((b<<6)|row)<<6) | t] = p / s;
  }
}

// ---------------- out_c = attn_c @ y  (+ fused BN2 stats) ----------------
// (verbatim round 2/4/6 — passed)
__global__ __launch_bounds__(256) void cam_apply_kernel(
    const float* __restrict__ attn, const float* __restrict__ y,
    float* __restrict__ oc, float* __restrict__ sums) {
  __shared__ float satt[64*68];
  int b = blockIdx.x >> 6;
  int n = ((blockIdx.x & 63) << 6) | (threadIdx.x & 63);
  int cg_ = threadIdx.x >> 6;
  for (int i = threadIdx.x; i < 4096; i += 256)
    satt[(i>>6)*68 + (i&63)] = attn[(b<<12) | i];
  __syncthreads();
  float yv[64];
  #pragma unroll
  for (int d = 0; d < 64; ++d) yv[d] = y[(((b<<6)|d)<<12) | n];
  for (int c = cg_*16; c < cg_*16+16; ++c) {
    float acc = 0.f;
    #pragma unroll
    for (int d4 = 0; d4 < 16; ++d4) {
      float4 avv = *(const float4*)&satt[c*68 + (d4<<2)];
      acc += avv.x*yv[d4*4] + avv.y*yv[d4*4+1] + avv.z*yv[d4*4+2] + avv.w*yv[d4*4+3];
    }
    oc[(((b<<6)|c)<<12) | n] = acc;
    float s1 = acc, s2 = acc*acc;
    #pragma unroll
    for (int off = 32; off; off >>= 1) { s1 += __shfl_xor(s1, off, 64); s2 += __shfl_xor(s2, off, 64); }
    if ((threadIdx.x & 63) == 0) { atomicAdd(&sums[c], s1); atomicAdd(&sums[64+c], s2); }
  }
}

// ---------------- fin: BN2 coefs + out = oc*A2 + B2 + y ----------------
// (verbatim round 4/6 — passed)
__global__ __launch_bounds__(256) void fin_kernel(
    const float* __restrict__ oc, const float* __restrict__ y,
    const float* __restrict__ s2b,
    const float* __restrict__ gc, const float* __restrict__ w2, const float* __restrict__ bb2,
    float* __restrict__ out) {
  __shared__ float cf[128];
  const int bi = blockIdx.x;
  const int b = bi >> 6, sp = bi & 63;
  const int t = threadIdx.x;
  const int n0 = sp << 6;
  if (t < 64) {
    float m1 = s2b[t] * (1.f/16384.f), m2 = s2b[64+t] * (1.f/16384.f);
    float var = m2 - m1*m1;
    float gg = *gc;
    float r = rsqrtf(gg*gg*var + EPS);
    float a = gg * r * w2[t];
    cf[t] = a; cf[64+t] = bb2[t] - m1*a;
  }
  __syncthreads();
  const int n = t & 63, cg_ = t >> 6;
  #pragma unroll
  for (int jj = 0; jj < 16; ++jj) {
    int c = (cg_<<4) + jj;              // wave-uniform c, lanes sweep n
    size_t gi = ((size_t)(((b<<6)|c)<<12)) + n0 + n;
    out[gi] = oc[gi]*cf[c] + cf[64+c] + y[gi];
  }
}

extern "C" void kernel_launch(void* const* d_in, const int* in_sizes, int n_in,
                              void* d_out, int out_size, void* d_ws, size_t ws_size,
                              hipStream_t stream) {
  (void)in_sizes; (void)n_in; (void)out_size; (void)ws_size;
  const float* x      = (const float*)d_in[0];
  const float* Wq     = (const float*)d_in[1];
  const float* bq     = (const float*)d_in[2];
  const float* Wk     = (const float*)d_in[3];
  const float* bk     = (const float*)d_in[4];
  const float* Wv     = (const float*)d_in[5];
  const float* bv     = (const float*)d_in[6];
  const float* gp     = (const float*)d_in[7];
  const float* bnp_w  = (const float*)d_in[8];
  const float* bnp_b  = (const float*)d_in[9];
  const float* gc     = (const float*)d_in[10];
  const float* bnc_w  = (const float*)d_in[11];
  const float* bnc_b  = (const float*)d_in[12];

  float* ws = (float*)d_ws;
  float* q     = ws + Q_OFF;
  float* k     = ws + K_OFF;
  float* v     = ws + V_OFF;
  float* o     = ws + O_OFF;
  float* y     = ws + Y_OFF;
  float* oc    = ws + OC_OFF;
  float* atc   = ws + AT_OFF;
  float* s2b   = ws + S2_OFF;
  float* ps    = ws + PS_OFF;
  float* gpart = ws + GP_OFF;

  // zero BN stat accumulators (s2b then ps, contiguous 256 floats)
  hipMemsetAsync(s2b, 0, 256u * sizeof(float), stream);

  proj_kernel<<<256, 256, 0, stream>>>(x, Wq, bq, Wk, bk, Wv, bv, q, k, v);
  attn_kernel<<<256, 256, 0, stream>>>(q, k, v, o, ps);
  yg_kernel<<<256, 256, 0, stream>>>(o, x, ps, gp, bnp_w, bnp_b, y, gpart);
  csm_kernel<<<256, 256, 0, stream>>>(gpart, atc);
  cam_apply_kernel<<<256, 256, 0, stream>>>(atc, y, oc, s2b);
  fin_kernel<<<256, 256, 0, stream>>>(oc, y, s2b, gc, bnc_w, bnc_b, (float*)d_out);
}

// Round 8
// 492.682 us; speedup vs baseline: 1.1066x; 1.1066x over previous
//
#include <hip/hip_runtime.h>

#define NN 4096
#define EPS 1e-5f

// ---------------- workspace layout (float offsets) ----------------
#define Q_OFF   0u              // [B][N][8]      131072
#define K_OFF   131072u         // [B][8][N]      131072
#define V_OFF   262144u         // [B][64][N]    1048576
#define O_OFF   1310720u        // PAM out [B][64][N]
#define Y_OFF   2359296u        // y [B][64][N]
#define OC_OFF  3407872u        // CAM raw out
#define AT_OFF  4456448u        // attn_c [B][64][64] 16384
#define S2_OFF  4472832u        // CAM sums: sum[64], sumsq[64]
#define PS_OFF  4472960u        // PAM sums: sum[64], sumsq[64]
#define CNT_OFF 4473088u        // per-(b,mt) arrival counters [256] int32
#define OP_OFF  4473344u        // attn partials [G=4][B][64mt][64m][64c] (4*1048576)
#define LP_OFF  8667648u        // partial row sums [G=4][B][64mt][64m] (4*16384)
// gpart ALIASES op region (op/lp dead after attn kernel completes)

// ---------------- projections: q,k,v (x staged via LDS) ----------------
// (verbatim round 6/7 — passed)
__global__ __launch_bounds__(256) void proj_kernel(
    const float* __restrict__ x, const float* __restrict__ Wq, const float* __restrict__ bq,
    const float* __restrict__ Wk, const float* __restrict__ bk,
    const float* __restrict__ Wv, const float* __restrict__ bv,
    float* __restrict__ q, float* __restrict__ k, float* __restrict__ v) {
  __shared__ float sWq[8*64], sWk[8*64], sWv[64*64], sbq[8], sbk[8], sbv[64];
  __shared__ float xt[64*68];
  int t = threadIdx.x;
  int b = blockIdx.x >> 6;
  int sp = blockIdx.x & 63;
  int n0 = sp << 6;
  for (int i = t; i < 512; i += 256) { sWq[i] = Wq[i]; sWk[i] = Wk[i]; }
  for (int i = t; i < 4096; i += 256) sWv[i] = Wv[i];
  if (t < 64) sbv[t] = bv[t];
  if (t < 8) { sbq[t] = bq[t]; sbk[t] = bk[t]; }
  for (int i = t; i < 1024; i += 256) {
    int c = i >> 4, nf = (i & 15) << 2;
    *(float4*)&xt[c*68 + nf] =
        *(const float4*)&x[(size_t)(((b<<6)|c)<<12) + n0 + nf];
  }
  __syncthreads();
  int nl = t & 63;
  int n = n0 | nl;
  int cg_ = t >> 6;
  float xv[64];
  #pragma unroll
  for (int c = 0; c < 64; ++c) xv[c] = xt[c*68 + nl];
  for (int c = cg_*16; c < cg_*16+16; ++c) {
    float acc = sbv[c];
    #pragma unroll
    for (int c2 = 0; c2 < 64; ++c2) acc += sWv[c*64 + c2] * xv[c2];
    v[(((b<<6)|c)<<12) | n] = acc;
  }
  if (cg_ == 0) {
    #pragma unroll
    for (int d = 0; d < 8; ++d) {
      float acc = sbq[d];
      #pragma unroll
      for (int c = 0; c < 64; ++c) acc += sWq[d*64+c] * xv[c];
      q[(((b<<12)|n)<<3) | d] = acc;
    }
  } else if (cg_ == 1) {
    #pragma unroll
    for (int d = 0; d < 8; ++d) {
      float acc = sbk[d];
      #pragma unroll
      for (int c = 0; c < 64; ++c) acc += sWk[d*64+c] * xv[c];
      k[(((b<<3)|d)<<12) | n] = acc;
    }
  }
}

// ---------------- flash attention (PAM), split-n + in-kernel last-block merge ----
// Core loop VERBATIM round 2 (198 us, VALU 55%, 4 blocks/CU).  G=4 hardcoded.
// After writing its partial, each block: syncthreads (drains vmcnt) ->
// thread0 release-fence + atomicAdd on cnt[(b,mt)].  The 4th arriver
// acquire-fences and merges the 4 partials inline (r2 merge body, LDS
// reused), writing o + fused BN1 stats.  No merge dispatch, no wait-for-all.
__global__ __launch_bounds__(256, 4) void attn_kernel(
    const float* __restrict__ q, const float* __restrict__ k,
    const float* __restrict__ v, float* __restrict__ op,
    float* __restrict__ lp, float* __restrict__ o,
    float* __restrict__ psums, int* __restrict__ cnt) {
  __shared__ float kst[64*12];   // [ni][d], pad 12; merge: linv[64]
  __shared__ float vst[64*68];   // [ni][c], pad 68; merge: sm[c][m] pad 65
  __shared__ float pst[64*68];   // [ni][m], pad 68 (+ lsum scratch)
  __shared__ int who;

  const int bi   = blockIdx.x;
  const int g    = bi & 3;
  const int rest = bi >> 2;
  const int mt   = rest & 63;
  const int b    = rest >> 6;
  const int m0   = mt << 6;
  const int t    = threadIdx.x;

  const int rq = t & 15;        // score: rows 4rq..4rq+3 ; PV: cols 4rq..
  const int sg = t >> 4;        // score: ni 4sg..4sg+3   ; PV: rows 4sg..

  float4 qa[4][2];
  #pragma unroll
  for (int r = 0; r < 4; ++r) {
    const float4* qp = (const float4*)&q[(size_t)(((b<<12) | (m0 + (rq<<2) + r)) << 3)];
    qa[r][0] = qp[0]; qa[r][1] = qp[1];
  }

  float lsum[4] = {0.f, 0.f, 0.f, 0.f};
  float av[4][4] = {{0.f}};

  const int span = NN >> 2;
  const int nbeg = g * span;

  for (int n0 = nbeg; n0 < nbeg + span; n0 += 64) {
    __syncthreads();             // prev PV reads of vst/pst done
    #pragma unroll
    for (int i = t; i < 512; i += 256) {
      int ni = i & 63, d = i >> 6;
      kst[ni*12 + d] = k[(((b<<3)|d)<<12) + n0 + ni];
    }
    #pragma unroll
    for (int i = t; i < 4096; i += 256) {
      int ni = i & 63, c = i >> 6;
      vst[ni*68 + c] = v[(((b<<6)|c)<<12) + n0 + ni];
    }
    __syncthreads();
    #pragma unroll
    for (int j = 0; j < 4; ++j) {
      const int ni = (sg << 2) | j;
      const float4 ka = *(const float4*)&kst[ni*12];
      const float4 kb = *(const float4*)&kst[ni*12 + 4];
      float pj[4];
      #pragma unroll
      for (int r = 0; r < 4; ++r) {
        float s = qa[r][0].x*ka.x + qa[r][0].y*ka.y + qa[r][0].z*ka.z + qa[r][0].w*ka.w
                + qa[r][1].x*kb.x + qa[r][1].y*kb.y + qa[r][1].z*kb.z + qa[r][1].w*kb.w;
        float e = __expf(s);     // no-max softmax (validated r1-r7)
        pj[r] = e;
        lsum[r] += e;
      }
      *(float4*)&pst[ni*68 + (rq<<2)] = make_float4(pj[0], pj[1], pj[2], pj[3]);
    }
    __syncthreads();
    #pragma unroll 4
    for (int ni = 0; ni < 64; ++ni) {
      const float4 p4 = *(const float4*)&pst[ni*68 + (sg<<2)];
      const float4 v4 = *(const float4*)&vst[ni*68 + (rq<<2)];
      av[0][0] += p4.x*v4.x; av[0][1] += p4.x*v4.y; av[0][2] += p4.x*v4.z; av[0][3] += p4.x*v4.w;
      av[1][0] += p4.y*v4.x; av[1][1] += p4.y*v4.y; av[1][2] += p4.y*v4.z; av[1][3] += p4.y*v4.w;
      av[2][0] += p4.z*v4.x; av[2][1] += p4.z*v4.y; av[2][2] += p4.z*v4.z; av[2][3] += p4.z*v4.w;
      av[3][0] += p4.w*v4.x; av[3][1] += p4.w*v4.y; av[3][2] += p4.w*v4.z; av[3][3] += p4.w*v4.w;
    }
  }
  __syncthreads();               // last PV reads done before pst reused
  // reduce lsum across the 16 sg groups via pst scratch, write lp partial
  *(float4*)&pst[sg*68 + (rq<<2)] = make_float4(lsum[0], lsum[1], lsum[2], lsum[3]);
  __syncthreads();
  if (t < 64) {
    float l = 0.f;
    #pragma unroll
    for (int s = 0; s < 16; ++s) l += pst[s*68 + t];
    lp[(((((g<<2)|b)<<6) | mt)<<6) | t] = l;
  }
  // write unnormalized partial av: op[g][b][mt][m][c]
  float* ob = op + ((size_t)((((g<<2)|b)<<6) | mt) << 12);
  #pragma unroll
  for (int r = 0; r < 4; ++r)
    *(float4*)&ob[((((sg<<2)|r)<<6) | (rq<<2))] =
        make_float4(av[r][0], av[r][1], av[r][2], av[r][3]);

  // ---- arrival protocol ----
  __syncthreads();               // all op/lp stores drained (vmcnt0 before barrier)
  if (t == 0) {
    __threadfence();             // release: make partial visible device-wide
    who = atomicAdd(&cnt[(b<<6) | mt], 1);
  }
  __syncthreads();
  if (who != 3) return;          // not the last arriver
  if (t == 0) __threadfence();   // acquire: invalidate caches before peer reads
  __syncthreads();

  // ---- inline merge (r2 merge_kernel body; vst->sm[c][m] pad65, kst->linv) ----
  float* sm = vst;
  float* linv = kst;
  if (t < 64) {
    float l = 0.f;
    #pragma unroll
    for (int g2 = 0; g2 < 4; ++g2)
      l += lp[(((((g2<<2)|b)<<6) | mt)<<6) | t];
    linv[t] = 1.f / l;
  }
  __syncthreads();
  for (int i = 0; i < 16; ++i) {
    int idx = (i<<8) + t;        // [m][c] row-major, coalesced per g
    float s = 0.f;
    #pragma unroll
    for (int g2 = 0; g2 < 4; ++g2)
      s += op[((size_t)((((g2<<2)|b)<<6) | mt) << 12) + idx];
    int m = idx >> 6, c = idx & 63;
    sm[c*65 + m] = s * linv[m];
  }
  __syncthreads();
  for (int i = 0; i < 16; ++i) {
    int idx = (i<<8) + t;
    int m = idx & 63, c = idx >> 6;    // c wave-uniform
    float ov = sm[c*65 + m];
    o[(((b<<6)|c)<<12) | (mt<<6) | m] = ov;
    float s1 = ov, s2 = ov*ov;
    #pragma unroll
    for (int off = 32; off; off >>= 1) {
      s1 += __shfl_xor(s1, off, 64);
      s2 += __shfl_xor(s2, off, 64);
    }
    if ((t & 63) == 0) { atomicAdd(&psums[c], s1); atomicAdd(&psums[64+c], s2); }
  }
}

// ---------------- yg: BN1 coefs + y = o*A1+B1+x + gram partials ----------------
// (verbatim round 4/6/7 — passed)
__global__ __launch_bounds__(256) void yg_kernel(
    const float* __restrict__ o, const float* __restrict__ x,
    const float* __restrict__ psums,
    const float* __restrict__ gp, const float* __restrict__ w1, const float* __restrict__ bb1,
    float* __restrict__ y, float* __restrict__ gpart) {
  __shared__ float yt[64*68];    // [c][m]
  __shared__ float cf[128];
  const int bi = blockIdx.x;
  const int b = bi >> 6, sp = bi & 63;
  const int t = threadIdx.x;
  const int n0 = sp << 6;
  if (t < 64) {
    float m1 = psums[t] * (1.f/16384.f), m2 = psums[64+t] * (1.f/16384.f);
    float var = m2 - m1*m1;
    float gg = *gp;
    float r = rsqrtf(gg*gg*var + EPS);
    float a = gg * r * w1[t];
    cf[t] = a; cf[64+t] = bb1[t] - m1*a;
  }
  __syncthreads();
  #pragma unroll
  for (int i = 0; i < 16; ++i) {
    int idx = (i<<8) + t;
    int c = idx >> 6, m = idx & 63;    // c wave-uniform, m coalesced
    size_t gi = ((size_t)(((b<<6)|c)<<12)) + n0 + m;
    float yv = o[gi]*cf[c] + cf[64+c] + x[gi];
    yt[c*68 + m] = yv;
    y[gi] = yv;
  }
  __syncthreads();
  {
    int tc = t >> 4, td = t & 15;
    float acc[4][4] = {{0.f}};
    #pragma unroll
    for (int mj = 0; mj < 16; ++mj) {
      float4 ya[4], yb[4];
      #pragma unroll
      for (int r = 0; r < 4; ++r)  ya[r] = *(const float4*)&yt[((tc<<2)+r)*68 + (mj<<2)];
      #pragma unroll
      for (int ss = 0; ss < 4; ++ss) yb[ss] = *(const float4*)&yt[((td<<2)+ss)*68 + (mj<<2)];
      #pragma unroll
      for (int r = 0; r < 4; ++r)
        #pragma unroll
        for (int ss = 0; ss < 4; ++ss)
          acc[r][ss] += ya[r].x*yb[ss].x + ya[r].y*yb[ss].y + ya[r].z*yb[ss].z + ya[r].w*yb[ss].w;
    }
    float* gb = gpart + ((size_t)bi << 12);
    #pragma unroll
    for (int r = 0; r < 4; ++r)
      *(float4*)&gb[(((tc<<2)+r)<<6) | (td<<2)] =
          make_float4(acc[r][0], acc[r][1], acc[r][2], acc[r][3]);
  }
}

// ---------------- csm: reduce gram partials + row softmax -> attnc ----------------
// (verbatim round 4/6/7 — passed)
__global__ __launch_bounds__(256) void csm_kernel(
    const float* __restrict__ gpart, float* __restrict__ attnc) {
  __shared__ float red[256];
  const int bi = blockIdx.x;
  const int b = bi >> 6, row = bi & 63;
  const int t = threadIdx.x;
  const int d = t & 63, spg = t >> 6;
  float e = 0.f;
  #pragma unroll
  for (int jj = 0; jj < 16; ++jj) {
    int spp = (spg<<4) + jj;
    e += gpart[((size_t)((b<<6)|spp) << 12) + (row<<6) + d];
  }
  red[t] = e;
  __syncthreads();
  if (t < 64) {
    float ee = red[t]+red[64+t]+red[128+t]+red[192+t];
    float mn = ee;
    #pragma unroll
    for (int off = 32; off; off >>= 1) mn = fminf(mn, __shfl_xor(mn, off, 64));
    float p = __expf(mn - ee);           // softmax(max-e) == exp(min-e)/sum
    float s = p;
    #pragma unroll
    for (int off = 32; off; off >>= 1) s += __shfl_xor(s, off, 64);
    attnc[(((b<<6)|row)<<6) | t] = p / s;
  }
}

// ---------------- out_c = attn_c @ y  (+ fused BN2 stats) ----------------
// (verbatim round 2/4/6/7 — passed)
__global__ __launch_bounds__(256) void cam_apply_kernel(
    const float* __restrict__ attn, const float* __restrict__ y,
    float* __restrict__ oc, float* __restrict__ sums) {
  __shared__ float satt[64*68];
  int b = blockIdx.x >> 6;
  int n = ((blockIdx.x & 63) << 6) | (threadIdx.x & 63);
  int cg_ = threadIdx.x >> 6;
  for (int i = threadIdx.x; i < 4096; i += 256)
    satt[(i>>6)*68 + (i&63)] = attn[(b<<12) | i];
  __syncthreads();
  float yv[64];
  #pragma unroll
  for (int d = 0; d < 64; ++d) yv[d] = y[(((b<<6)|d)<<12) | n];
  for (int c = cg_*16; c < cg_*16+16; ++c) {
    float acc = 0.f;
    #pragma unroll
    for (int d4 = 0; d4 < 16; ++d4) {
      float4 avv = *(const float4*)&satt[c*68 + (d4<<2)];
      acc += avv.x*yv[d4*4] + avv.y*yv[d4*4+1] + avv.z*yv[d4*4+2] + avv.w*yv[d4*4+3];
    }
    oc[(((b<<6)|c)<<12) | n] = acc;
    float s1 = acc, s2 = acc*acc;
    #pragma unroll
    for (int off = 32; off; off >>= 1) { s1 += __shfl_xor(s1, off, 64); s2 += __shfl_xor(s2, off, 64); }
    if ((threadIdx.x & 63) == 0) { atomicAdd(&sums[c], s1); atomicAdd(&sums[64+c], s2); }
  }
}

// ---------------- fin: BN2 coefs + out = oc*A2 + B2 + y ----------------
// (verbatim round 4/6/7 — passed)
__global__ __launch_bounds__(256) void fin_kernel(
    const float* __restrict__ oc, const float* __restrict__ y,
    const float* __restrict__ s2b,
    const float* __restrict__ gc, const float* __restrict__ w2, const float* __restrict__ bb2,
    float* __restrict__ out) {
  __shared__ float cf[128];
  const int bi = blockIdx.x;
  const int b = bi >> 6, sp = bi & 63;
  const int t = threadIdx.x;
  const int n0 = sp << 6;
  if (t < 64) {
    float m1 = s2b[t] * (1.f/16384.f), m2 = s2b[64+t] * (1.f/16384.f);
    float var = m2 - m1*m1;
    float gg = *gc;
    float r = rsqrtf(gg*gg*var + EPS);
    float a = gg * r * w2[t];
    cf[t] = a; cf[64+t] = bb2[t] - m1*a;
  }
  __syncthreads();
  const int n = t & 63, cg_ = t >> 6;
  #pragma unroll
  for (int jj = 0; jj < 16; ++jj) {
    int c = (cg_<<4) + jj;              // wave-uniform c, lanes sweep n
    size_t gi = ((size_t)(((b<<6)|c)<<12)) + n0 + n;
    out[gi] = oc[gi]*cf[c] + cf[64+c] + y[gi];
  }
}

extern "C" void kernel_launch(void* const* d_in, const int* in_sizes, int n_in,
                              void* d_out, int out_size, void* d_ws, size_t ws_size,
                              hipStream_t stream) {
  (void)in_sizes; (void)n_in; (void)out_size; (void)ws_size;
  const float* x      = (const float*)d_in[0];
  const float* Wq     = (const float*)d_in[1];
  const float* bq     = (const float*)d_in[2];
  const float* Wk     = (const float*)d_in[3];
  const float* bk     = (const float*)d_in[4];
  const float* Wv     = (const float*)d_in[5];
  const float* bv     = (const float*)d_in[6];
  const float* gp     = (const float*)d_in[7];
  const float* bnp_w  = (const float*)d_in[8];
  const float* bnp_b  = (const float*)d_in[9];
  const float* gc     = (const float*)d_in[10];
  const float* bnc_w  = (const float*)d_in[11];
  const float* bnc_b  = (const float*)d_in[12];

  float* ws = (float*)d_ws;
  float* q     = ws + Q_OFF;
  float* k     = ws + K_OFF;
  float* v     = ws + V_OFF;
  float* o     = ws + O_OFF;
  float* y     = ws + Y_OFF;
  float* oc    = ws + OC_OFF;
  float* atc   = ws + AT_OFF;
  float* s2b   = ws + S2_OFF;
  float* ps    = ws + PS_OFF;
  int*   cnt   = (int*)(ws + CNT_OFF);
  float* op    = ws + OP_OFF;
  float* lpart = ws + LP_OFF;
  float* gpart = op;             // aliases op region (dead after attn)

  // zero s2b(128) + ps(128) + cnt(256) — contiguous 512 words
  hipMemsetAsync(s2b, 0, 512u * sizeof(float), stream);

  proj_kernel<<<256, 256, 0, stream>>>(x, Wq, bq, Wk, bk, Wv, bv, q, k, v);
  attn_kernel<<<1024, 256, 0, stream>>>(q, k, v, op, lpart, o, ps, cnt);
  yg_kernel<<<256, 256, 0, stream>>>(o, x, ps, gp, bnp_w, bnp_b, y, gpart);
  csm_kernel<<<256, 256, 0, stream>>>(gpart, atc);
  cam_apply_kernel<<<256, 256, 0, stream>>>(atc, y, oc, s2b);
  fin_kernel<<<256, 256, 0, stream>>>(oc, y, s2b, gc, bnc_w, bnc_b, (float*)d_out);
}

// Round 10
// 474.425 us; speedup vs baseline: 1.1492x; 1.0385x over previous
//
#include <hip/hip_runtime.h>

#define NN 4096
#define EPS 1e-5f

typedef unsigned long long u64;
union f2u { float f[2]; u64 u; };

// ---------------- workspace layout (float offsets) ----------------
#define Q_OFF   0u              // [B][N][8]      131072
#define K_OFF   131072u         // [B][8][N]      131072
#define V_OFF   262144u         // [B][64][N]    1048576
#define O_OFF   1310720u        // PAM out [B][64][N]
#define Y_OFF   2359296u        // y [B][64][N]
#define OC_OFF  3407872u        // CAM raw out
#define AT_OFF  4456448u        // attn_c [B][64][64] 16384
#define S2_OFF  4472832u        // CAM sums: sum[64], sumsq[64]
#define PS_OFF  4472960u        // PAM sums: sum[64], sumsq[64]
#define CNT_OFF 4473088u        // per-(b,mt) arrival counters [256] int32
#define OP_OFF  4473344u        // attn partials [G=4][B][64mt][64m][64c] (4*1048576)
#define LP_OFF  8667648u        // partial row sums [G=4][B][64mt][64m] (4*16384)
// gpart ALIASES op region (op/lp dead after attn kernel completes)

// ---------------- projections: q,k,v (x staged via LDS) ----------------
// (verbatim round 6/7/8 — passed)
__global__ __launch_bounds__(256) void proj_kernel(
    const float* __restrict__ x, const float* __restrict__ Wq, const float* __restrict__ bq,
    const float* __restrict__ Wk, const float* __restrict__ bk,
    const float* __restrict__ Wv, const float* __restrict__ bv,
    float* __restrict__ q, float* __restrict__ k, float* __restrict__ v) {
  __shared__ float sWq[8*64], sWk[8*64], sWv[64*64], sbq[8], sbk[8], sbv[64];
  __shared__ float xt[64*68];
  int t = threadIdx.x;
  int b = blockIdx.x >> 6;
  int sp = blockIdx.x & 63;
  int n0 = sp << 6;
  for (int i = t; i < 512; i += 256) { sWq[i] = Wq[i]; sWk[i] = Wk[i]; }
  for (int i = t; i < 4096; i += 256) sWv[i] = Wv[i];
  if (t < 64) sbv[t] = bv[t];
  if (t < 8) { sbq[t] = bq[t]; sbk[t] = bk[t]; }
  for (int i = t; i < 1024; i += 256) {
    int c = i >> 4, nf = (i & 15) << 2;
    *(float4*)&xt[c*68 + nf] =
        *(const float4*)&x[(size_t)(((b<<6)|c)<<12) + n0 + nf];
  }
  __syncthreads();
  int nl = t & 63;
  int n = n0 | nl;
  int cg_ = t >> 6;
  float xv[64];
  #pragma unroll
  for (int c = 0; c < 64; ++c) xv[c] = xt[c*68 + nl];
  for (int c = cg_*16; c < cg_*16+16; ++c) {
    float acc = sbv[c];
    #pragma unroll
    for (int c2 = 0; c2 < 64; ++c2) acc += sWv[c*64 + c2] * xv[c2];
    v[(((b<<6)|c)<<12) | n] = acc;
  }
  if (cg_ == 0) {
    #pragma unroll
    for (int d = 0; d < 8; ++d) {
      float acc = sbq[d];
      #pragma unroll
      for (int c = 0; c < 64; ++c) acc += sWq[d*64+c] * xv[c];
      q[(((b<<12)|n)<<3) | d] = acc;
    }
  } else if (cg_ == 1) {
    #pragma unroll
    for (int d = 0; d < 8; ++d) {
      float acc = sbk[d];
      #pragma unroll
      for (int c = 0; c < 64; ++c) acc += sWk[d*64+c] * xv[c];
      k[(((b<<3)|d)<<12) | n] = acc;
    }
  }
}

// ---------------- flash attention (PAM), split-n + in-kernel last-block merge ----
// Core loop VERBATIM round 2 (198 us, VALU 55%, 4 blocks/CU).  G=4 hardcoded.
// Sync protocol (r8/r9 lessons combined):
//  - partials written with device-scope RELAXED atomic stores (sc0 sc1 ->
//    coherence point; L2 stays clean, so the release wbl2 below is ~free)
//  - arrival: t0 fetch_add with RELEASE (orders the stores; cheap since no
//    dirty L2, unlike r8's threadfence which flushed 16MB of dirty partials)
//  - last arriver only: ACQUIRE fence (buffer_inv) -> kills any stale clean
//    L2 lines for op/lp left by the PREVIOUS LAUNCH's merge reads (this was
//    r9's second-run corruption), then plain float4 loads for the merge.
__global__ __launch_bounds__(256, 4) void attn_kernel(
    const float* __restrict__ q, const float* __restrict__ k,
    const float* __restrict__ v, float* __restrict__ op,
    float* __restrict__ lp, float* __restrict__ o,
    float* __restrict__ psums, int* __restrict__ cnt) {
  __shared__ float kst[64*12];   // [ni][d], pad 12; merge: linv[64]
  __shared__ float vst[64*68];   // [ni][c], pad 68; merge: sm[c][m] pad 65
  __shared__ float pst[64*68];   // [ni][m], pad 68 (+ lsum scratch)
  __shared__ int who;

  const int bi   = blockIdx.x;
  const int g    = bi & 3;
  const int rest = bi >> 2;
  const int mt   = rest & 63;
  const int b    = rest >> 6;
  const int m0   = mt << 6;
  const int t    = threadIdx.x;

  const int rq = t & 15;        // score: rows 4rq..4rq+3 ; PV: cols 4rq..
  const int sg = t >> 4;        // score: ni 4sg..4sg+3   ; PV: rows 4sg..

  float4 qa[4][2];
  #pragma unroll
  for (int r = 0; r < 4; ++r) {
    const float4* qp = (const float4*)&q[(size_t)(((b<<12) | (m0 + (rq<<2) + r)) << 3)];
    qa[r][0] = qp[0]; qa[r][1] = qp[1];
  }

  float lsum[4] = {0.f, 0.f, 0.f, 0.f};
  float av[4][4] = {{0.f}};

  const int span = NN >> 2;
  const int nbeg = g * span;

  for (int n0 = nbeg; n0 < nbeg + span; n0 += 64) {
    __syncthreads();             // prev PV reads of vst/pst done
    #pragma unroll
    for (int i = t; i < 512; i += 256) {
      int ni = i & 63, d = i >> 6;
      kst[ni*12 + d] = k[(((b<<3)|d)<<12) + n0 + ni];
    }
    #pragma unroll
    for (int i = t; i < 4096; i += 256) {
      int ni = i & 63, c = i >> 6;
      vst[ni*68 + c] = v[(((b<<6)|c)<<12) + n0 + ni];
    }
    __syncthreads();
    #pragma unroll
    for (int j = 0; j < 4; ++j) {
      const int ni = (sg << 2) | j;
      const float4 ka = *(const float4*)&kst[ni*12];
      const float4 kb = *(const float4*)&kst[ni*12 + 4];
      float pj[4];
      #pragma unroll
      for (int r = 0; r < 4; ++r) {
        float s = qa[r][0].x*ka.x + qa[r][0].y*ka.y + qa[r][0].z*ka.z + qa[r][0].w*ka.w
                + qa[r][1].x*kb.x + qa[r][1].y*kb.y + qa[r][1].z*kb.z + qa[r][1].w*kb.w;
        float e = __expf(s);     // no-max softmax (validated r1-r8)
        pj[r] = e;
        lsum[r] += e;
      }
      *(float4*)&pst[ni*68 + (rq<<2)] = make_float4(pj[0], pj[1], pj[2], pj[3]);
    }
    __syncthreads();
    #pragma unroll 4
    for (int ni = 0; ni < 64; ++ni) {
      const float4 p4 = *(const float4*)&pst[ni*68 + (sg<<2)];
      const float4 v4 = *(const float4*)&vst[ni*68 + (rq<<2)];
      av[0][0] += p4.x*v4.x; av[0][1] += p4.x*v4.y; av[0][2] += p4.x*v4.z; av[0][3] += p4.x*v4.w;
      av[1][0] += p4.y*v4.x; av[1][1] += p4.y*v4.y; av[1][2] += p4.y*v4.z; av[1][3] += p4.y*v4.w;
      av[2][0] += p4.z*v4.x; av[2][1] += p4.z*v4.y; av[2][2] += p4.z*v4.z; av[2][3] += p4.z*v4.w;
      av[3][0] += p4.w*v4.x; av[3][1] += p4.w*v4.y; av[3][2] += p4.w*v4.z; av[3][3] += p4.w*v4.w;
    }
  }
  __syncthreads();               // last PV reads done before pst reused
  // reduce lsum across the 16 sg groups via pst scratch, write lp partial
  *(float4*)&pst[sg*68 + (rq<<2)] = make_float4(lsum[0], lsum[1], lsum[2], lsum[3]);
  __syncthreads();
  if (t < 64) {
    float l = 0.f;
    #pragma unroll
    for (int s = 0; s < 16; ++s) l += pst[s*68 + t];
    __hip_atomic_store(&lp[(((((g<<2)|b)<<6) | mt)<<6) | t], l,
                       __ATOMIC_RELAXED, __HIP_MEMORY_SCOPE_AGENT);
  }
  // write unnormalized partial av (device-scope relaxed, 8B granules, L2-clean)
  float* ob = op + ((size_t)((((g<<2)|b)<<6) | mt) << 12);
  #pragma unroll
  for (int r = 0; r < 4; ++r) {
    const int base = (((sg<<2)|r)<<6) | (rq<<2);
    f2u lo, hi;
    lo.f[0] = av[r][0]; lo.f[1] = av[r][1];
    hi.f[0] = av[r][2]; hi.f[1] = av[r][3];
    __hip_atomic_store((u64*)&ob[base],     lo.u, __ATOMIC_RELAXED, __HIP_MEMORY_SCOPE_AGENT);
    __hip_atomic_store((u64*)&ob[base + 2], hi.u, __ATOMIC_RELAXED, __HIP_MEMORY_SCOPE_AGENT);
  }

  // ---- arrival protocol ----
  __syncthreads();               // all waves' stores issued before arrival
  if (t == 0)
    who = __hip_atomic_fetch_add(&cnt[(b<<6) | mt], 1,
                                 __ATOMIC_RELEASE, __HIP_MEMORY_SCOPE_AGENT);
  __syncthreads();
  if (who != 3) return;          // not the last arriver
  if (t == 0)
    __builtin_amdgcn_fence(__ATOMIC_ACQUIRE, "agent");  // buffer_inv: drop stale L2
  __syncthreads();

  // ---- inline merge (plain vector loads — L2 just invalidated, reads fresh) ----
  float* sm = vst;
  float* linv = kst;
  if (t < 64) {
    float l = 0.f;
    #pragma unroll
    for (int g2 = 0; g2 < 4; ++g2)
      l += lp[(((((g2<<2)|b)<<6) | mt)<<6) | t];
    linv[t] = 1.f / l;
  }
  __syncthreads();
  for (int i = 0; i < 16; ++i) {
    int idx = (i<<8) + t;        // [m][c] row-major, coalesced per g
    float s = 0.f;
    #pragma unroll
    for (int g2 = 0; g2 < 4; ++g2)
      s += op[((size_t)((((g2<<2)|b)<<6) | mt) << 12) + idx];
    int m = idx >> 6, c = idx & 63;
    sm[c*65 + m] = s * linv[m];
  }
  __syncthreads();
  for (int i = 0; i < 16; ++i) {
    int idx = (i<<8) + t;
    int m = idx & 63, c = idx >> 6;    // c wave-uniform
    float ov = sm[c*65 + m];
    o[(((b<<6)|c)<<12) | (mt<<6) | m] = ov;
    float s1 = ov, s2 = ov*ov;
    #pragma unroll
    for (int off2 = 32; off2; off2 >>= 1) {
      s1 += __shfl_xor(s1, off2, 64);
      s2 += __shfl_xor(s2, off2, 64);
    }
    if ((t & 63) == 0) { atomicAdd(&psums[c], s1); atomicAdd(&psums[64+c], s2); }
  }
}

// ---------------- yg: BN1 coefs + y = o*A1+B1+x + gram partials ----------------
// (verbatim round 4/6/7/8 — passed)
__global__ __launch_bounds__(256) void yg_kernel(
    const float* __restrict__ o, const float* __restrict__ x,
    const float* __restrict__ psums,
    const float* __restrict__ gp, const float* __restrict__ w1, const float* __restrict__ bb1,
    float* __restrict__ y, float* __restrict__ gpart) {
  __shared__ float yt[64*68];    // [c][m]
  __shared__ float cf[128];
  const int bi = blockIdx.x;
  const int b = bi >> 6, sp = bi & 63;
  const int t = threadIdx.x;
  const int n0 = sp << 6;
  if (t < 64) {
    float m1 = psums[t] * (1.f/16384.f), m2 = psums[64+t] * (1.f/16384.f);
    float var = m2 - m1*m1;
    float gg = *gp;
    float r = rsqrtf(gg*gg*var + EPS);
    float a = gg * r * w1[t];
    cf[t] = a; cf[64+t] = bb1[t] - m1*a;
  }
  __syncthreads();
  #pragma unroll
  for (int i = 0; i < 16; ++i) {
    int idx = (i<<8) + t;
    int c = idx >> 6, m = idx & 63;    // c wave-uniform, m coalesced
    size_t gi = ((size_t)(((b<<6)|c)<<12)) + n0 + m;
    float yv = o[gi]*cf[c] + cf[64+c] + x[gi];
    yt[c*68 + m] = yv;
    y[gi] = yv;
  }
  __syncthreads();
  {
    int tc = t >> 4, td = t & 15;
    float acc[4][4] = {{0.f}};
    #pragma unroll
    for (int mj = 0; mj < 16; ++mj) {
      float4 ya[4], yb[4];
      #pragma unroll
      for (int r = 0; r < 4; ++r)  ya[r] = *(const float4*)&yt[((tc<<2)+r)*68 + (mj<<2)];
      #pragma unroll
      for (int ss = 0; ss < 4; ++ss) yb[ss] = *(const float4*)&yt[((td<<2)+ss)*68 + (mj<<2)];
      #pragma unroll
      for (int r = 0; r < 4; ++r)
        #pragma unroll
        for (int ss = 0; ss < 4; ++ss)
          acc[r][ss] += ya[r].x*yb[ss].x + ya[r].y*yb[ss].y + ya[r].z*yb[ss].z + ya[r].w*yb[ss].w;
    }
    float* gb = gpart + ((size_t)bi << 12);
    #pragma unroll
    for (int r = 0; r < 4; ++r)
      *(float4*)&gb[(((tc<<2)+r)<<6) | (td<<2)] =
          make_float4(acc[r][0], acc[r][1], acc[r][2], acc[r][3]);
  }
}

// ---------------- csm: reduce gram partials + row softmax -> attnc ----------------
// (verbatim round 4/6/7/8 — passed)
__global__ __launch_bounds__(256) void csm_kernel(
    const float* __restrict__ gpart, float* __restrict__ attnc) {
  __shared__ float red[256];
  const int bi = blockIdx.x;
  const int b = bi >> 6, row = bi & 63;
  const int t = threadIdx.x;
  const int d = t & 63, spg = t >> 6;
  float e = 0.f;
  #pragma unroll
  for (int jj = 0; jj < 16; ++jj) {
    int spp = (spg<<4) + jj;
    e += gpart[((size_t)((b<<6)|spp) << 12) + (row<<6) + d];
  }
  red[t] = e;
  __syncthreads();
  if (t < 64) {
    float ee = red[t]+red[64+t]+red[128+t]+red[192+t];
    float mn = ee;
    #pragma unroll
    for (int off = 32; off; off >>= 1) mn = fminf(mn, __shfl_xor(mn, off, 64));
    float p = __expf(mn - ee);           // softmax(max-e) == exp(min-e)/sum
    float s = p;
    #pragma unroll
    for (int off = 32; off; off >>= 1) s += __shfl_xor(s, off, 64);
    attnc[(((b<<6)|row)<<6) | t] = p / s;
  }
}

// ---------------- out_c = attn_c @ y  (+ fused BN2 stats) ----------------
// (verbatim round 2/4/6/7/8 — passed)
__global__ __launch_bounds__(256) void cam_apply_kernel(
    const float* __restrict__ attn, const float* __restrict__ y,
    float* __restrict__ oc, float* __restrict__ sums) {
  __shared__ float satt[64*68];
  int b = blockIdx.x >> 6;
  int n = ((blockIdx.x & 63) << 6) | (threadIdx.x & 63);
  int cg_ = threadIdx.x >> 6;
  for (int i = threadIdx.x; i < 4096; i += 256)
    satt[(i>>6)*68 + (i&63)] = attn[(b<<12) | i];
  __syncthreads();
  float yv[64];
  #pragma unroll
  for (int d = 0; d < 64; ++d) yv[d] = y[(((b<<6)|d)<<12) | n];
  for (int c = cg_*16; c < cg_*16+16; ++c) {
    float acc = 0.f;
    #pragma unroll
    for (int d4 = 0; d4 < 16; ++d4) {
      float4 avv = *(const float4*)&satt[c*68 + (d4<<2)];
      acc += avv.x*yv[d4*4] + avv.y*yv[d4*4+1] + avv.z*yv[d4*4+2] + avv.w*yv[d4*4+3];
    }
    oc[(((b<<6)|c)<<12) | n] = acc;
    float s1 = acc, s2 = acc*acc;
    #pragma unroll
    for (int off = 32; off; off >>= 1) { s1 += __shfl_xor(s1, off, 64); s2 += __shfl_xor(s2, off, 64); }
    if ((threadIdx.x & 63) == 0) { atomicAdd(&sums[c], s1); atomicAdd(&sums[64+c], s2); }
  }
}

// ---------------- fin: BN2 coefs + out = oc*A2 + B2 + y ----------------
// (verbatim round 4/6/7/8 — passed)
__global__ __launch_bounds__(256) void fin_kernel(
    const float* __restrict__ oc, const float* __restrict__ y,
    const float* __restrict__ s2b,
    const float* __restrict__ gc, const float* __restrict__ w2, const float* __restrict__ bb2,
    float* __restrict__ out) {
  __shared__ float cf[128];
  const int bi = blockIdx.x;
  const int b = bi >> 6, sp = bi & 63;
  const int t = threadIdx.x;
  const int n0 = sp << 6;
  if (t < 64) {
    float m1 = s2b[t] * (1.f/16384.f), m2 = s2b[64+t] * (1.f/16384.f);
    float var = m2 - m1*m1;
    float gg = *gc;
    float r = rsqrtf(gg*gg*var + EPS);
    float a = gg * r * w2[t];
    cf[t] = a; cf[64+t] = bb2[t] - m1*a;
  }
  __syncthreads();
  const int n = t & 63, cg_ = t >> 6;
  #pragma unroll
  for (int jj = 0; jj < 16; ++jj) {
    int c = (cg_<<4) + jj;              // wave-uniform c, lanes sweep n
    size_t gi = ((size_t)(((b<<6)|c)<<12)) + n0 + n;
    out[gi] = oc[gi]*cf[c] + cf[64+c] + y[gi];
  }
}

extern "C" void kernel_launch(void* const* d_in, const int* in_sizes, int n_in,
                              void* d_out, int out_size, void* d_ws, size_t ws_size,
                              hipStream_t stream) {
  (void)in_sizes; (void)n_in; (void)out_size; (void)ws_size;
  const float* x      = (const float*)d_in[0];
  const float* Wq     = (const float*)d_in[1];
  const float* bq     = (const float*)d_in[2];
  const float* Wk     = (const float*)d_in[3];
  const float* bk     = (const float*)d_in[4];
  const float* Wv     = (const float*)d_in[5];
  const float* bv     = (const float*)d_in[6];
  const float* gp     = (const float*)d_in[7];
  const float* bnp_w  = (const float*)d_in[8];
  const float* bnp_b  = (const float*)d_in[9];
  const float* gc     = (const float*)d_in[10];
  const float* bnc_w  = (const float*)d_in[11];
  const float* bnc_b  = (const float*)d_in[12];

  float* ws = (float*)d_ws;
  float* q     = ws + Q_OFF;
  float* k     = ws + K_OFF;
  float* v     = ws + V_OFF;
  float* o     = ws + O_OFF;
  float* y     = ws + Y_OFF;
  float* oc    = ws + OC_OFF;
  float* atc   = ws + AT_OFF;
  float* s2b   = ws + S2_OFF;
  float* ps    = ws + PS_OFF;
  int*   cnt   = (int*)(ws + CNT_OFF);
  float* op    = ws + OP_OFF;
  float* lpart = ws + LP_OFF;
  float* gpart = op;             // aliases op region (dead after attn)

  // zero s2b(128) + ps(128) + cnt(256) — contiguous 512 words
  hipMemsetAsync(s2b, 0, 512u * sizeof(float), stream);

  proj_kernel<<<256, 256, 0, stream>>>(x, Wq, bq, Wk, bk, Wv, bv, q, k, v);
  attn_kernel<<<1024, 256, 0, stream>>>(q, k, v, op, lpart, o, ps, cnt);
  yg_kernel<<<256, 256, 0, stream>>>(o, x, ps, gp, bnp_w, bnp_b, y, gpart);
  csm_kernel<<<256, 256, 0, stream>>>(gpart, atc);
  cam_apply_kernel<<<256, 256, 0, stream>>>(atc, y, oc, s2b);
  fin_kernel<<<256, 256, 0, stream>>>(oc, y, s2b, gc, bnc_w, bnc_b, (float*)d_out);
}